// Round 9
// baseline (387.781 us; speedup 1.0000x reference)
//
#include <hip/hip_runtime.h>
#include <cmath>

#define B_    16
#define HH    56
#define WWI   56
#define C_    256
#define NH_   8
#define WS_   7
#define SS_   3
#define HD_   32
#define NTOK  50176          // B*56*56
#define NN    49             // window size squared
#define SCALE_ 0.17677669529663689f
#define EPS_  1e-5f

typedef __bf16  bf16x8  __attribute__((ext_vector_type(8)));
typedef float   f32x4   __attribute__((ext_vector_type(4)));
typedef unsigned short ushort8v __attribute__((ext_vector_type(8)));

__device__ __forceinline__ unsigned short f2bf(float f) {
    unsigned int u = __float_as_uint(f);
    unsigned int r = u + 0x7FFFu + ((u >> 16) & 1u);   // RNE
    return (unsigned short)(r >> 16);
}
__device__ __forceinline__ float bf2f(unsigned short h) {
    return __uint_as_float(((unsigned int)h) << 16);
}
// tanh-form GELU: |err| <= ~3e-3 vs exact erf form; hw v_exp_f32 + rcp
__device__ __forceinline__ float gelu_t(float x) {
    float t = 0.7978845608028654f * (x + 0.044715f * x * x * x);
    float e = __expf(2.0f * t);
    float th = 1.0f - 2.0f * __builtin_amdgcn_rcpf(e + 1.0f);
    return 0.5f * x * (1.0f + th);
}

// async global->LDS DMA, 16B per lane; deposits at wave-uniform lds base + lane*16
__device__ __forceinline__ void gload_lds16(const unsigned short* g, unsigned short* l) {
    __builtin_amdgcn_global_load_lds(
        (const __attribute__((address_space(1))) unsigned int*)g,
        (__attribute__((address_space(3))) unsigned int*)l, 16, 0, 0);
}

// ---------------- fused prep: weights fp32->bf16 + rel-bias/mask table -------
__global__ __launch_bounds__(256) void prep_k(
    const float* __restrict__ qkvw, const float* __restrict__ projw,
    const float* __restrict__ fc1w, const float* __restrict__ fc2w,
    unsigned short* __restrict__ dst,
    const float* __restrict__ mask, const float* __restrict__ relb,
    unsigned short* __restrict__ cb)
{
    if (blockIdx.x < 3072) {
        int i = blockIdx.x * 256 + threadIdx.x;          // < 786432
        float v;
        if      (i < 196608) v = qkvw[i];
        else if (i < 262144) v = projw[i - 196608];
        else if (i < 524288) v = fc1w[i - 262144];
        else                 v = fc2w[i - 524288];
        dst[i] = f2bf(v);
    } else {
        int s = blockIdx.x - 3072;          // 512 slices = 64 windows * 8 heads
        int wi = s >> 3, head = s & 7;
        for (int p = threadIdx.x; p < 2408; p += 256) {
            float v = 0.0f;
            if (p < 2401) {
                int i = p / NN, j = p - i * NN;
                int di = i / 7 - j / 7 + 6, dj = i % 7 - j % 7 + 6;
                v = relb[(di * 13 + dj) * NH_ + head] + mask[(size_t)wi * 2401 + p];
            }
            cb[(size_t)s * 2408 + p] = f2bf(v);
        }
    }
}

// ---------------- LayerNorm1 (shift+window-partition) ------------------------
__global__ __launch_bounds__(256) void ln_k(
    const float* __restrict__ x, const float* __restrict__ g,
    const float* __restrict__ bta, unsigned short* __restrict__ dst)
{
    int wave = threadIdx.x >> 6, lane = threadIdx.x & 63;
    int tok = blockIdx.x * 4 + wave;                  // < 50176
    const float4 v = *(const float4*)(x + (size_t)tok * C_ + lane * 4);
    float s = v.x + v.y + v.z + v.w;
    float q = v.x*v.x + v.y*v.y + v.z*v.z + v.w*v.w;
    for (int o = 32; o > 0; o >>= 1) { s += __shfl_xor(s, o, 64); q += __shfl_xor(q, o, 64); }
    float mu  = s * (1.0f / C_);
    float var = q * (1.0f / C_) - mu * mu;
    float rs  = rsqrtf(var + EPS_);
    float4 gg = *(const float4*)(g   + lane * 4);
    float4 bb = *(const float4*)(bta + lane * 4);
    float y0 = (v.x - mu) * rs * gg.x + bb.x;
    float y1 = (v.y - mu) * rs * gg.y + bb.y;
    float y2 = (v.z - mu) * rs * gg.z + bb.z;
    float y3 = (v.w - mu) * rs * gg.w + bb.w;
    int b = tok / 3136, p = tok % 3136;
    int ph = p / 56, pw = p % 56;
    int sh = ph - SS_; if (sh < 0) sh += HH;
    int sw = pw - SS_; if (sw < 0) sw += WWI;
    int bw = b * 64 + (sh / WS_) * 8 + (sw / WS_);
    int n  = (sh % WS_) * WS_ + (sw % WS_);
    size_t di = ((size_t)bw * NN + n) * C_ + lane * 4;
    unsigned int lo = (unsigned int)f2bf(y0) | ((unsigned int)f2bf(y1) << 16);
    unsigned int hi = (unsigned int)f2bf(y2) | ((unsigned int)f2bf(y3) << 16);
    uint2 u; u.x = lo; u.y = hi;
    *(uint2*)(dst + di) = u;
}

// ---------------- MFMA GEMM, 128x128, BK=32, depth-2 DMA, 4 blk/CU -----------
// R5 config (kept for low-epilogue-VALU GEMMs: QKV EPI=0, FC2 EPI=3).
// T2 swizzle: slot q of row r holds global chunk q ^ ((r>>1)&3); linear LDS
// dest, pre-permuted per-lane global source; frag reads undo via sw8.
template<int EPI, int NT>
__global__ __launch_bounds__(256, 4) void gemm_k(
    const unsigned short* __restrict__ A, const unsigned short* __restrict__ Bt,
    int K, const float* __restrict__ bias,
    const float* __restrict__ resid, float* __restrict__ outF,
    unsigned short* __restrict__ outQ, unsigned short* __restrict__ outK,
    unsigned short* __restrict__ outV)
{
    __shared__ __align__(16) unsigned char smem[32768];
    const int tid = threadIdx.x;
    const int lin = blockIdx.x;
    const int xcd = lin & 7, t = lin >> 3;
    const int m0 = (xcd * 49 + t / NT) * 128;
    const int n0 = (t % NT) * 128;
    const int wave = tid >> 6, lane = tid & 63, quad = lane >> 4, l16 = lane & 15;
    const int wm = wave >> 1, wn = wave & 1;
    const int r0 = tid >> 2;
    const int c0 = (((tid & 3) ^ ((tid >> 3) & 3)) * 8);

    const size_t gA0 = (size_t)(m0 + r0) * K + c0;
    const size_t gA1 = (size_t)(m0 + r0 + 64) * K + c0;
    const size_t gB0 = (size_t)(n0 + r0) * K + c0;
    const size_t gB1 = (size_t)(n0 + r0 + 64) * K + c0;
    const int woff = wave * 512;
    const int sw8 = (quad ^ ((l16 >> 1) & 3)) * 8;

    f32x4 acc[4][4] = {};
    const int nk = K >> 5;

    #define STAGE(kt_, p_) { \
        unsigned short* sA_ = (unsigned short*)(smem + (p_) * 16384); \
        unsigned short* sB_ = sA_ + 4096; \
        const int kp_ = (kt_) << 5; \
        gload_lds16(A + gA0 + kp_, sA_ + woff); \
        gload_lds16(A + gA1 + kp_, sA_ + woff + 2048); \
        gload_lds16(Bt + gB0 + kp_, sB_ + woff); \
        gload_lds16(Bt + gB1 + kp_, sB_ + woff + 2048); }

    STAGE(0, 0);
    for (int kk = 0; kk < nk; ++kk) {
        const int p = kk & 1;
        if (kk + 1 < nk) {
            STAGE(kk + 1, p ^ 1);
            __asm volatile("s_waitcnt vmcnt(4)\n\ts_barrier" ::: "memory");
        } else {
            __asm volatile("s_waitcnt vmcnt(0)\n\ts_barrier" ::: "memory");
        }
        const unsigned short* sA = (const unsigned short*)(smem + p * 16384);
        const unsigned short* sB = sA + 4096;
        bf16x8 af[4], bfr[4];
        #pragma unroll
        for (int tt = 0; tt < 4; ++tt) {
            af[tt]  = __builtin_bit_cast(bf16x8, *(const ushort8v*)(sA + (wm * 64 + tt * 16 + l16) * 32 + sw8));
            bfr[tt] = __builtin_bit_cast(bf16x8, *(const ushort8v*)(sB + (wn * 64 + tt * 16 + l16) * 32 + sw8));
        }
        #pragma unroll
        for (int mt = 0; mt < 4; ++mt)
            #pragma unroll
            for (int nt = 0; nt < 4; ++nt)
                acc[mt][nt] = __builtin_amdgcn_mfma_f32_16x16x32_bf16(af[mt], bfr[nt], acc[mt][nt], 0, 0, 0);
        __asm volatile("s_barrier" ::: "memory");
    }
    #undef STAGE

    float b4[4];
    #pragma unroll
    for (int nt = 0; nt < 4; ++nt) b4[nt] = bias[n0 + wn * 64 + nt * 16 + l16];

    // ---- bf16 output: two 64-row passes through LDS, packed uint4 ----
    unsigned short (*swB)[136] = (unsigned short (*)[136])smem;  // 64x136x2 = 17408B
    const int seg = n0 >> 8;                      // EPI0: 0=q 1=k 2=v
    const float qs = (EPI == 0 && seg == 0) ? SCALE_ : 1.0f;
    #pragma unroll
    for (int p = 0; p < 2; ++p) {
        __syncthreads();
        if (wm == p) {
            #pragma unroll
            for (int mt = 0; mt < 4; ++mt)
                #pragma unroll
                for (int nt = 0; nt < 4; ++nt)
                    #pragma unroll
                    for (int r = 0; r < 4; ++r) {
                        float v = acc[mt][nt][r] + b4[nt];
                        if (EPI == 0) v *= qs;
                        swB[mt * 16 + quad * 4 + r][wn * 64 + nt * 16 + l16] = f2bf(v);
                    }
        }
        __syncthreads();
        if (EPI == 0) {
            unsigned short* dstp = seg == 0 ? outQ : (seg == 1 ? outK : outV);
            const int nbase = n0 & 255;
            for (int tt = tid; tt < 1024; tt += 256) {
                int row = tt >> 4, c8 = (tt & 15) * 8;
                int m = m0 + p * 64 + row, bw = m / NN, nw = m - bw * NN;
                int cc = nbase + c8;
                uint4 u = *(uint4*)&swB[row][c8];
                *(uint4*)&dstp[(((size_t)bw * NH_ + (cc >> 5)) * NN + nw) * HD_ + (cc & 31)] = u;
            }
        } else {
            // EPI==3: FC2 adds into outF (residual RMW)
            for (int tt = tid; tt < 1024; tt += 256) {
                int row = tt >> 4, c8 = (tt & 15) * 8;
                size_t adr = (size_t)(m0 + p * 64 + row) * C_ + n0 + c8;
                float4 u0, u1;
                unsigned short* sp8 = &swB[row][c8];
                u0.x = bf2f(sp8[0]); u0.y = bf2f(sp8[1]); u0.z = bf2f(sp8[2]); u0.w = bf2f(sp8[3]);
                u1.x = bf2f(sp8[4]); u1.y = bf2f(sp8[5]); u1.z = bf2f(sp8[6]); u1.w = bf2f(sp8[7]);
                const float4 r0_ = *(const float4*)&outF[adr];
                const float4 r1_ = *(const float4*)&outF[adr + 4];
                u0.x += r0_.x; u0.y += r0_.y; u0.z += r0_.z; u0.w += r0_.w;
                u1.x += r1_.x; u1.y += r1_.y; u1.z += r1_.z; u1.w += r1_.w;
                *(float4*)&outF[adr] = u0;
                *(float4*)&outF[adr + 4] = u1;
            }
        }
    }
}

// ---------------- MFMA GEMM, 128x128, BK=32, depth-3 DMA (R2 config) ---------
// FC1 (GELU epilogue, ~33.5us fixed VALU): depth-3 hides a full extra step of
// staging latency; measured 62.3us in R2 vs 70.5us with depth-2 (R5).
template<int NT>
__global__ __launch_bounds__(256) void gemm3_k(
    const unsigned short* __restrict__ A, const unsigned short* __restrict__ Bt,
    int K, const float* __restrict__ bias, unsigned short* __restrict__ outB)
{
    __shared__ __align__(16) unsigned char smem[49152];
    const int tid = threadIdx.x;
    const int lin = blockIdx.x;
    const int xcd = lin & 7, t = lin >> 3;
    const int m0 = (xcd * 49 + t / NT) * 128;
    const int n0 = (t % NT) * 128;
    const int wave = tid >> 6, lane = tid & 63, quad = lane >> 4, l16 = lane & 15;
    const int wm = wave >> 1, wn = wave & 1;
    const int r0 = tid >> 2;
    const int c0 = (((tid & 3) ^ ((tid >> 3) & 3)) * 8);

    const size_t gA0 = (size_t)(m0 + r0) * K + c0;
    const size_t gA1 = (size_t)(m0 + r0 + 64) * K + c0;
    const size_t gB0 = (size_t)(n0 + r0) * K + c0;
    const size_t gB1 = (size_t)(n0 + r0 + 64) * K + c0;
    const int woff = wave * 512;
    const int sw8 = (quad ^ ((l16 >> 1) & 3)) * 8;

    f32x4 acc[4][4] = {};
    const int nk = K >> 5;
    #pragma unroll
    for (int p = 0; p < 2; ++p) {
        unsigned short* sA = (unsigned short*)(smem + p * 16384);
        unsigned short* sB = sA + 4096;
        const int kp = p << 5;
        gload_lds16(A + gA0 + kp, sA + woff);
        gload_lds16(A + gA1 + kp, sA + woff + 2048);
        gload_lds16(Bt + gB0 + kp, sB + woff);
        gload_lds16(Bt + gB1 + kp, sB + woff + 2048);
    }
    int bufc = 0;
    for (int kk = 0; kk < nk; ++kk) {
        if (kk + 2 < nk) {
            int bufn = bufc + 2; if (bufn >= 3) bufn -= 3;
            unsigned short* sA = (unsigned short*)(smem + bufn * 16384);
            unsigned short* sB = sA + 4096;
            const int k2 = (kk + 2) << 5;
            gload_lds16(A + gA0 + k2, sA + woff);
            gload_lds16(A + gA1 + k2, sA + woff + 2048);
            gload_lds16(Bt + gB0 + k2, sB + woff);
            gload_lds16(Bt + gB1 + k2, sB + woff + 2048);
            __asm volatile("s_waitcnt vmcnt(8)\n\ts_barrier" ::: "memory");
        } else if (kk + 1 < nk) {
            __asm volatile("s_waitcnt vmcnt(4)\n\ts_barrier" ::: "memory");
        } else {
            __asm volatile("s_waitcnt vmcnt(0)\n\ts_barrier" ::: "memory");
        }
        const unsigned short* sA = (const unsigned short*)(smem + bufc * 16384);
        const unsigned short* sB = sA + 4096;
        bf16x8 af[4], bfr[4];
        #pragma unroll
        for (int tt = 0; tt < 4; ++tt) {
            af[tt]  = __builtin_bit_cast(bf16x8, *(const ushort8v*)(sA + (wm * 64 + tt * 16 + l16) * 32 + sw8));
            bfr[tt] = __builtin_bit_cast(bf16x8, *(const ushort8v*)(sB + (wn * 64 + tt * 16 + l16) * 32 + sw8));
        }
        #pragma unroll
        for (int mt = 0; mt < 4; ++mt)
            #pragma unroll
            for (int nt = 0; nt < 4; ++nt)
                acc[mt][nt] = __builtin_amdgcn_mfma_f32_16x16x32_bf16(af[mt], bfr[nt], acc[mt][nt], 0, 0, 0);
        __asm volatile("s_barrier" ::: "memory");
        if (++bufc == 3) bufc = 0;
    }

    float b4[4];
    #pragma unroll
    for (int nt = 0; nt < 4; ++nt) b4[nt] = bias[n0 + wn * 64 + nt * 16 + l16];

    unsigned short (*swB)[136] = (unsigned short (*)[136])smem;  // 128x136x2 = 34816B
    #pragma unroll
    for (int mt = 0; mt < 4; ++mt)
        #pragma unroll
        for (int nt = 0; nt < 4; ++nt)
            #pragma unroll
            for (int r = 0; r < 4; ++r) {
                float v = gelu_t(acc[mt][nt][r] + b4[nt]);
                swB[wm * 64 + mt * 16 + quad * 4 + r][wn * 64 + nt * 16 + l16] = f2bf(v);
            }
    __syncthreads();
    for (int tt = tid; tt < 2048; tt += 256) {
        int row = tt >> 4, c8 = (tt & 15) * 8;
        uint4 u = *(uint4*)&swB[row][c8];
        *(uint4*)&outB[(size_t)(m0 + row) * 1024 + n0 + c8] = u;
    }
}

// ---------------- proj GEMM (128x256) + residual + fused LayerNorm2 ----------
// BN=256 => each block owns full rows; epilogue computes u = x + proj + bias,
// writes out (fp32) AND h2 = LN2(u) (bf16), killing the standalone LN2 kernel
// and its 51MB fp32 re-read. One row per wave in the LN pass (lane=col/4).
__global__ __launch_bounds__(256) void projln_k(
    const unsigned short* __restrict__ A, const unsigned short* __restrict__ Bt,
    const float* __restrict__ bias, const float* __restrict__ resid,
    const float* __restrict__ g2, const float* __restrict__ b2,
    float* __restrict__ outF, unsigned short* __restrict__ h2)
{
    __shared__ __align__(16) unsigned char smem[49152];   // 2 x 24KB staging
    const int tid = threadIdx.x;
    const int lin = blockIdx.x;              // 392 = 8 * 49
    const int xcd = lin & 7, t = lin >> 3;
    const int m0 = (xcd * 49 + t) * 128;
    const int wave = tid >> 6, lane = tid & 63, quad = lane >> 4, l16 = lane & 15;
    const int wm = wave >> 1, wn = wave & 1;     // wave: 64 rows x 128 cols
    const int r0 = tid >> 2;
    const int c0 = (((tid & 3) ^ ((tid >> 3) & 3)) * 8);
    const int K = 256;
    const size_t gA0 = (size_t)(m0 + r0) * K + c0;
    const size_t gA1 = (size_t)(m0 + r0 + 64) * K + c0;
    const size_t gB0 = (size_t)(r0)       * K + c0;
    const size_t gB1 = (size_t)(r0 + 64)  * K + c0;
    const size_t gB2 = (size_t)(r0 + 128) * K + c0;
    const size_t gB3 = (size_t)(r0 + 192) * K + c0;
    const int woff = wave * 512;             // shorts
    const int sw8 = (quad ^ ((l16 >> 1) & 3)) * 8;

    f32x4 acc[4][8] = {};
    const int nk = 8;                        // K=256, BK=32

    #define PSTG(kt_, p_) { \
        unsigned short* sA_ = (unsigned short*)(smem + (p_) * 24576); \
        unsigned short* sB_ = sA_ + 4096; \
        const int kp_ = (kt_) << 5; \
        gload_lds16(A  + gA0 + kp_, sA_ + woff); \
        gload_lds16(A  + gA1 + kp_, sA_ + woff + 2048); \
        gload_lds16(Bt + gB0 + kp_, sB_ + woff); \
        gload_lds16(Bt + gB1 + kp_, sB_ + woff + 2048); \
        gload_lds16(Bt + gB2 + kp_, sB_ + woff + 4096); \
        gload_lds16(Bt + gB3 + kp_, sB_ + woff + 6144); }

    PSTG(0, 0);
    for (int kk = 0; kk < nk; ++kk) {
        const int p = kk & 1;
        if (kk + 1 < nk) {
            PSTG(kk + 1, p ^ 1);
            __asm volatile("s_waitcnt vmcnt(6)\n\ts_barrier" ::: "memory");
        } else {
            __asm volatile("s_waitcnt vmcnt(0)\n\ts_barrier" ::: "memory");
        }
        const unsigned short* sA = (const unsigned short*)(smem + p * 24576);
        const unsigned short* sB = sA + 4096;
        bf16x8 af[4], bfr[8];
        #pragma unroll
        for (int tt = 0; tt < 4; ++tt)
            af[tt]  = __builtin_bit_cast(bf16x8, *(const ushort8v*)(sA + (wm * 64 + tt * 16 + l16) * 32 + sw8));
        #pragma unroll
        for (int nt = 0; nt < 8; ++nt)
            bfr[nt] = __builtin_bit_cast(bf16x8, *(const ushort8v*)(sB + (wn * 128 + nt * 16 + l16) * 32 + sw8));
        #pragma unroll
        for (int mt = 0; mt < 4; ++mt)
            #pragma unroll
            for (int nt = 0; nt < 8; ++nt)
                acc[mt][nt] = __builtin_amdgcn_mfma_f32_16x16x32_bf16(af[mt], bfr[nt], acc[mt][nt], 0, 0, 0);
        __asm volatile("s_barrier" ::: "memory");
    }
    #undef PSTG

    float b8[8];
    #pragma unroll
    for (int nt = 0; nt < 8; ++nt) b8[nt] = bias[wn * 128 + nt * 16 + l16];
    const float4 g4  = *(const float4*)&g2[lane * 4];
    const float4 bb4 = *(const float4*)&b2[lane * 4];

    float (*swF)[260] = (float (*)[260])smem;      // 32 x 260 x 4 = 33280B
    #pragma unroll
    for (int p = 0; p < 4; ++p) {
        __syncthreads();
        if (wm == (p >> 1)) {
            const int mtb = (p & 1) * 2;
            #pragma unroll
            for (int mt = 0; mt < 2; ++mt)
                #pragma unroll
                for (int nt = 0; nt < 8; ++nt)
                    #pragma unroll
                    for (int r = 0; r < 4; ++r)
                        swF[mt * 16 + quad * 4 + r][wn * 128 + nt * 16 + l16] =
                            acc[mtb + mt][nt][r] + b8[nt];
        }
        __syncthreads();
        #pragma unroll
        for (int i = 0; i < 8; ++i) {
            int r32 = i * 4 + wave;                      // one row per wave
            int m = m0 + p * 32 + r32;
            int bw = m / NN, nw = m - bw * NN;
            int b = bw >> 6, wi = bw & 63;
            int sh = (wi >> 3) * WS_ + nw / WS_;
            int sw = (wi & 7) * WS_ + nw % WS_;
            int ph = sh + SS_; if (ph >= HH)  ph -= HH;
            int pw = sw + SS_; if (pw >= WWI) pw -= WWI;
            size_t rowadr = ((size_t)b * 3136 + ph * 56 + pw) * C_;
            float4 v = *(float4*)&swF[r32][lane * 4];
            const float4 rr = *(const float4*)&resid[rowadr + lane * 4];
            v.x += rr.x; v.y += rr.y; v.z += rr.z; v.w += rr.w;
            *(float4*)&outF[rowadr + lane * 4] = v;
            float s = v.x + v.y + v.z + v.w;
            float q = v.x*v.x + v.y*v.y + v.z*v.z + v.w*v.w;
            #pragma unroll
            for (int o = 32; o > 0; o >>= 1) { s += __shfl_xor(s, o, 64); q += __shfl_xor(q, o, 64); }
            float mu  = s * (1.0f / C_);
            float var = q * (1.0f / C_) - mu * mu;
            float rs  = rsqrtf(var + EPS_);
            float y0 = (v.x - mu) * rs * g4.x + bb4.x;
            float y1 = (v.y - mu) * rs * g4.y + bb4.y;
            float y2 = (v.z - mu) * rs * g4.z + bb4.z;
            float y3 = (v.w - mu) * rs * g4.w + bb4.w;
            unsigned int lo = (unsigned int)f2bf(y0) | ((unsigned int)f2bf(y1) << 16);
            unsigned int hi = (unsigned int)f2bf(y2) | ((unsigned int)f2bf(y3) << 16);
            uint2 uu; uu.x = lo; uu.y = hi;
            *(uint2*)&h2[rowadr + lane * 4] = uu;
        }
    }
}

// ---------------- MFMA attention: one block per (window, head) ----------------
__global__ __launch_bounds__(256) void attn_k(
    const unsigned short* __restrict__ qb, const unsigned short* __restrict__ kb,
    const unsigned short* __restrict__ vb, const unsigned short* __restrict__ cb,
    unsigned short* __restrict__ ob)
{
    __shared__ unsigned short qs[64][40];   // Q rows (pad 40: frag reads 2-way free)
    __shared__ unsigned short ks[64][40];   // K rows
    __shared__ unsigned short vt[32][72];   // V^T: [d][j], j padded to 64 (zeroed 49..63)
    __shared__ unsigned short sp[64][72];   // P bf16, A-layout rows
    __shared__ unsigned short cbs[2408];    // bias+mask slice
    const int tid = threadIdx.x;
    const int bw = blockIdx.x >> 3, head = blockIdx.x & 7;
    const size_t base = (size_t)blockIdx.x * (NN * HD_);   // (bw*8+head)*1568

    for (int t = tid; t < 588; t += 256) {
        int seg = t / 196, idx = t - seg * 196;
        int e = idx * 8;                          // 8 shorts = 16B
        const unsigned short* src = (seg == 0 ? qb : seg == 1 ? kb : vb) + base + e;
        uint4 u = *(const uint4*)src;
        if (seg == 0)      *(uint4*)&qs[e >> 5][e & 31] = u;
        else if (seg == 1) *(uint4*)&ks[e >> 5][e & 31] = u;
        else {
            int n = e >> 5, hd = e & 31;
            const unsigned short* pu = (const unsigned short*)&u;
            #pragma unroll
            for (int uu = 0; uu < 8; ++uu) vt[hd + uu][n] = pu[uu];
        }
    }
    {
        const unsigned short* cbase = cb + (size_t)(((bw & 63) * 8 + head)) * 2408;
        for (int t = tid; t < 301; t += 256)
            *(uint4*)&cbs[t * 8] = *(const uint4*)(cbase + t * 8);
        for (int t = tid; t < 480; t += 256) vt[t / 15][NN + t % 15] = 0;  // zero j=49..63
    }
    __syncthreads();

    const int wave = tid >> 6, lane = tid & 63, quad = lane >> 4, l16 = lane & 15;
    const f32x4 zz = {};

    bf16x8 afq = __builtin_bit_cast(bf16x8, *(const ushort8v*)&qs[wave * 16 + l16][quad * 8]);
    f32x4 s4[4];
    #pragma unroll
    for (int jt = 0; jt < 4; ++jt) {
        bf16x8 bk = __builtin_bit_cast(bf16x8, *(const ushort8v*)&ks[jt * 16 + l16][quad * 8]);
        s4[jt] = __builtin_amdgcn_mfma_f32_16x16x32_bf16(afq, bk, zz, 0, 0, 0);
    }

    #pragma unroll
    for (int r = 0; r < 4; ++r) {
        int i = wave * 16 + quad * 4 + r;
        float vals[4];
        #pragma unroll
        for (int jt = 0; jt < 4; ++jt) {
            int j = jt * 16 + l16;
            vals[jt] = (i < NN && j < NN) ? s4[jt][r] + bf2f(cbs[i * NN + j]) : -1e30f;
        }
        float mx = fmaxf(fmaxf(vals[0], vals[1]), fmaxf(vals[2], vals[3]));
        #pragma unroll
        for (int o = 1; o < 16; o <<= 1) mx = fmaxf(mx, __shfl_xor(mx, o, 64));
        float e[4], sum = 0.0f;
        #pragma unroll
        for (int jt = 0; jt < 4; ++jt) { e[jt] = __expf(vals[jt] - mx); sum += e[jt]; }
        #pragma unroll
        for (int o = 1; o < 16; o <<= 1) sum += __shfl_xor(sum, o, 64);
        float inv = 1.0f / sum;
        #pragma unroll
        for (int jt = 0; jt < 4; ++jt) sp[i][jt * 16 + l16] = f2bf(e[jt] * inv);
    }
    __syncthreads();

    bf16x8 ap[2];
    #pragma unroll
    for (int kt = 0; kt < 2; ++kt)
        ap[kt] = __builtin_bit_cast(bf16x8, *(const ushort8v*)&sp[wave * 16 + l16][kt * 32 + quad * 8]);
    f32x4 o4[2] = {};
    #pragma unroll
    for (int nt = 0; nt < 2; ++nt)
        #pragma unroll
        for (int kt = 0; kt < 2; ++kt) {
            bf16x8 bv = __builtin_bit_cast(bf16x8, *(const ushort8v*)&vt[nt * 16 + l16][kt * 32 + quad * 8]);
            o4[nt] = __builtin_amdgcn_mfma_f32_16x16x32_bf16(ap[kt], bv, o4[nt], 0, 0, 0);
        }
    #pragma unroll
    for (int nt = 0; nt < 2; ++nt)
        #pragma unroll
        for (int r = 0; r < 4; ++r) {
            int i = wave * 16 + quad * 4 + r;
            if (i < NN)
                ob[((size_t)bw * NN + i) * C_ + head * HD_ + nt * 16 + l16] = f2bf(o4[nt][r]);
        }
}

extern "C" void kernel_launch(void* const* d_in, const int* in_sizes, int n_in,
                              void* d_out, int out_size, void* d_ws, size_t ws_size,
                              hipStream_t stream)
{
    const float* x     = (const float*)d_in[0];
    const float* mask  = (const float*)d_in[1];
    const float* n1g   = (const float*)d_in[2];
    const float* n1b   = (const float*)d_in[3];
    const float* qkvw  = (const float*)d_in[4];
    const float* qkvb  = (const float*)d_in[5];
    const float* relb  = (const float*)d_in[6];
    const float* projw = (const float*)d_in[7];
    const float* projb = (const float*)d_in[8];
    const float* n2g   = (const float*)d_in[9];
    const float* n2b   = (const float*)d_in[10];
    const float* fc1w  = (const float*)d_in[11];
    const float* fc1b  = (const float*)d_in[12];
    const float* fc2w  = (const float*)d_in[13];
    const float* fc2b  = (const float*)d_in[14];
    float* out = (float*)d_out;

    unsigned short* wq = (unsigned short*)d_ws;   // all weights bf16, contiguous
    unsigned short* wp = wq + 196608;
    unsigned short* w1 = wq + 262144;
    unsigned short* w2 = wq + 524288;
    unsigned short* hw = wq + 786432;             // LN1-shift-partitioned (50176,256) bf16
    unsigned short* qb = hw + 12845056;           // (1024,8,49,32) bf16
    unsigned short* kb = qb + 12845056;
    unsigned short* vb = kb + 12845056;
    unsigned short* ob = vb + 12845056;           // attn out, windowed (50176,256) bf16
    unsigned short* h2 = ob + 12845056;           // LN2 out (50176,256) bf16
    unsigned short* a1 = h2 + 12845056;           // GELU(fc1) (50176,1024) bf16
    unsigned short* cbt = a1;                     // cb aliases a1 (attn_k finishes before FC1 writes a1)

    prep_k<<<3584, 256, 0, stream>>>(qkvw, projw, fc1w, fc2w, wq, mask, relb, cbt);
    ln_k<<<12544, 256, 0, stream>>>(x, n1g, n1b, hw);
    gemm_k<0, 6><<<392 * 6, 256, 0, stream>>>(hw, wq, 256, qkvb, nullptr, nullptr, qb, kb, vb);
    attn_k<<<8192, 256, 0, stream>>>(qb, kb, vb, cbt, ob);
    projln_k<<<392, 256, 0, stream>>>(ob, wp, projb, x, n2g, n2b, out, h2);
    gemm3_k<8><<<392 * 8, 256, 0, stream>>>(h2, w1, 256, fc1b, a1);
    gemm_k<3, 2><<<392 * 2, 256, 0, stream>>>(a1, w2, 1024, fc2b, nullptr, out, nullptr, nullptr, nullptr);
}

// Round 14
// 376.461 us; speedup vs baseline: 1.0301x; 1.0301x over previous
//
#include <hip/hip_runtime.h>
#include <cmath>

#define B_    16
#define HH    56
#define WWI   56
#define C_    256
#define NH_   8
#define WS_   7
#define SS_   3
#define HD_   32
#define NTOK  50176          // B*56*56
#define NN    49             // window size squared
#define SCALE_ 0.17677669529663689f
#define EPS_  1e-5f

typedef __bf16  bf16x8  __attribute__((ext_vector_type(8)));
typedef float   f32x4   __attribute__((ext_vector_type(4)));
typedef unsigned short ushort8v __attribute__((ext_vector_type(8)));

__device__ __forceinline__ unsigned short f2bf(float f) {
    unsigned int u = __float_as_uint(f);
    unsigned int r = u + 0x7FFFu + ((u >> 16) & 1u);   // RNE
    return (unsigned short)(r >> 16);
}
__device__ __forceinline__ float bf2f(unsigned short h) {
    return __uint_as_float(((unsigned int)h) << 16);
}
// tanh-form GELU: |err| <= ~3e-3 vs exact erf form; hw v_exp_f32 + rcp
__device__ __forceinline__ float gelu_t(float x) {
    float t = 0.7978845608028654f * (x + 0.044715f * x * x * x);
    float e = __expf(2.0f * t);
    float th = 1.0f - 2.0f * __builtin_amdgcn_rcpf(e + 1.0f);
    return 0.5f * x * (1.0f + th);
}

// async global->LDS DMA, 16B per lane; deposits at wave-uniform lds base + lane*16
__device__ __forceinline__ void gload_lds16(const unsigned short* g, unsigned short* l) {
    __builtin_amdgcn_global_load_lds(
        (const __attribute__((address_space(1))) unsigned int*)g,
        (__attribute__((address_space(3))) unsigned int*)l, 16, 0, 0);
}

// ---------------- fused prep: weights fp32->bf16 + rel-bias/mask table -------
__global__ __launch_bounds__(256) void prep_k(
    const float* __restrict__ qkvw, const float* __restrict__ projw,
    const float* __restrict__ fc1w, const float* __restrict__ fc2w,
    unsigned short* __restrict__ dst,
    const float* __restrict__ mask, const float* __restrict__ relb,
    unsigned short* __restrict__ cb)
{
    if (blockIdx.x < 3072) {
        int i = blockIdx.x * 256 + threadIdx.x;          // < 786432
        float v;
        if      (i < 196608) v = qkvw[i];
        else if (i < 262144) v = projw[i - 196608];
        else if (i < 524288) v = fc1w[i - 262144];
        else                 v = fc2w[i - 524288];
        dst[i] = f2bf(v);
    } else {
        int s = blockIdx.x - 3072;          // 512 slices = 64 windows * 8 heads
        int wi = s >> 3, head = s & 7;
        for (int p = threadIdx.x; p < 2408; p += 256) {
            float v = 0.0f;
            if (p < 2401) {
                int i = p / NN, j = p - i * NN;
                int di = i / 7 - j / 7 + 6, dj = i % 7 - j % 7 + 6;
                v = relb[(di * 13 + dj) * NH_ + head] + mask[(size_t)wi * 2401 + p];
            }
            cb[(size_t)s * 2408 + p] = f2bf(v);
        }
    }
}

// ---------------- LayerNorm1 (shift+window-partition) ------------------------
__global__ __launch_bounds__(256) void ln_k(
    const float* __restrict__ x, const float* __restrict__ g,
    const float* __restrict__ bta, unsigned short* __restrict__ dst)
{
    int wave = threadIdx.x >> 6, lane = threadIdx.x & 63;
    int tok = blockIdx.x * 4 + wave;                  // < 50176
    const float4 v = *(const float4*)(x + (size_t)tok * C_ + lane * 4);
    float s = v.x + v.y + v.z + v.w;
    float q = v.x*v.x + v.y*v.y + v.z*v.z + v.w*v.w;
    for (int o = 32; o > 0; o >>= 1) { s += __shfl_xor(s, o, 64); q += __shfl_xor(q, o, 64); }
    float mu  = s * (1.0f / C_);
    float var = q * (1.0f / C_) - mu * mu;
    float rs  = rsqrtf(var + EPS_);
    float4 gg = *(const float4*)(g   + lane * 4);
    float4 bb = *(const float4*)(bta + lane * 4);
    float y0 = (v.x - mu) * rs * gg.x + bb.x;
    float y1 = (v.y - mu) * rs * gg.y + bb.y;
    float y2 = (v.z - mu) * rs * gg.z + bb.z;
    float y3 = (v.w - mu) * rs * gg.w + bb.w;
    int b = tok / 3136, p = tok % 3136;
    int ph = p / 56, pw = p % 56;
    int sh = ph - SS_; if (sh < 0) sh += HH;
    int sw = pw - SS_; if (sw < 0) sw += WWI;
    int bw = b * 64 + (sh / WS_) * 8 + (sw / WS_);
    int n  = (sh % WS_) * WS_ + (sw % WS_);
    size_t di = ((size_t)bw * NN + n) * C_ + lane * 4;
    unsigned int lo = (unsigned int)f2bf(y0) | ((unsigned int)f2bf(y1) << 16);
    unsigned int hi = (unsigned int)f2bf(y2) | ((unsigned int)f2bf(y3) << 16);
    uint2 u; u.x = lo; u.y = hi;
    *(uint2*)(dst + di) = u;
}

// ---------------- MFMA GEMM, 128x128, BK=32, depth-2 DMA, 4 blk/CU -----------
// QKV (EPI=0, bf16 out) and FC2 (EPI=3, fp32 RMW). FC2 epilogue restored to
// the R5-measured fp32 4x32-row float4 path (R9's bf16 bounce + scalar
// ds_read_u16 cost +12us and 100K bank conflicts).
// T2 swizzle: slot q of row r holds global chunk q ^ ((r>>1)&3); linear LDS
// dest, pre-permuted per-lane global source; frag reads undo via sw8.
template<int EPI, int NT>
__global__ __launch_bounds__(256, 4) void gemm_k(
    const unsigned short* __restrict__ A, const unsigned short* __restrict__ Bt,
    int K, const float* __restrict__ bias,
    float* __restrict__ outF,
    unsigned short* __restrict__ outQ, unsigned short* __restrict__ outK,
    unsigned short* __restrict__ outV)
{
    __shared__ __align__(16) unsigned char smem[32768];
    const int tid = threadIdx.x;
    const int lin = blockIdx.x;
    const int xcd = lin & 7, t = lin >> 3;
    const int m0 = (xcd * 49 + t / NT) * 128;
    const int n0 = (t % NT) * 128;
    const int wave = tid >> 6, lane = tid & 63, quad = lane >> 4, l16 = lane & 15;
    const int wm = wave >> 1, wn = wave & 1;
    const int r0 = tid >> 2;
    const int c0 = (((tid & 3) ^ ((tid >> 3) & 3)) * 8);

    const size_t gA0 = (size_t)(m0 + r0) * K + c0;
    const size_t gA1 = (size_t)(m0 + r0 + 64) * K + c0;
    const size_t gB0 = (size_t)(n0 + r0) * K + c0;
    const size_t gB1 = (size_t)(n0 + r0 + 64) * K + c0;
    const int woff = wave * 512;
    const int sw8 = (quad ^ ((l16 >> 1) & 3)) * 8;

    f32x4 acc[4][4] = {};
    const int nk = K >> 5;

    #define STAGE(kt_, p_) { \
        unsigned short* sA_ = (unsigned short*)(smem + (p_) * 16384); \
        unsigned short* sB_ = sA_ + 4096; \
        const int kp_ = (kt_) << 5; \
        gload_lds16(A + gA0 + kp_, sA_ + woff); \
        gload_lds16(A + gA1 + kp_, sA_ + woff + 2048); \
        gload_lds16(Bt + gB0 + kp_, sB_ + woff); \
        gload_lds16(Bt + gB1 + kp_, sB_ + woff + 2048); }

    STAGE(0, 0);
    for (int kk = 0; kk < nk; ++kk) {
        const int p = kk & 1;
        if (kk + 1 < nk) {
            STAGE(kk + 1, p ^ 1);
            __asm volatile("s_waitcnt vmcnt(4)\n\ts_barrier" ::: "memory");
        } else {
            __asm volatile("s_waitcnt vmcnt(0)\n\ts_barrier" ::: "memory");
        }
        const unsigned short* sA = (const unsigned short*)(smem + p * 16384);
        const unsigned short* sB = sA + 4096;
        bf16x8 af[4], bfr[4];
        #pragma unroll
        for (int tt = 0; tt < 4; ++tt) {
            af[tt]  = __builtin_bit_cast(bf16x8, *(const ushort8v*)(sA + (wm * 64 + tt * 16 + l16) * 32 + sw8));
            bfr[tt] = __builtin_bit_cast(bf16x8, *(const ushort8v*)(sB + (wn * 64 + tt * 16 + l16) * 32 + sw8));
        }
        #pragma unroll
        for (int mt = 0; mt < 4; ++mt)
            #pragma unroll
            for (int nt = 0; nt < 4; ++nt)
                acc[mt][nt] = __builtin_amdgcn_mfma_f32_16x16x32_bf16(af[mt], bfr[nt], acc[mt][nt], 0, 0, 0);
        __asm volatile("s_barrier" ::: "memory");
    }
    #undef STAGE

    float b4[4];
    #pragma unroll
    for (int nt = 0; nt < 4; ++nt) b4[nt] = bias[n0 + wn * 64 + nt * 16 + l16];

    if (EPI == 0) {
        // ---- bf16 output: two 64-row passes through LDS, packed uint4 ----
        unsigned short (*swB)[136] = (unsigned short (*)[136])smem;  // 64x136x2 = 17408B
        const int seg = n0 >> 8;                      // 0=q 1=k 2=v
        const float qs = (seg == 0) ? SCALE_ : 1.0f;
        #pragma unroll
        for (int p = 0; p < 2; ++p) {
            __syncthreads();
            if (wm == p) {
                #pragma unroll
                for (int mt = 0; mt < 4; ++mt)
                    #pragma unroll
                    for (int nt = 0; nt < 4; ++nt)
                        #pragma unroll
                        for (int r = 0; r < 4; ++r) {
                            float v = (acc[mt][nt][r] + b4[nt]) * qs;
                            swB[mt * 16 + quad * 4 + r][wn * 64 + nt * 16 + l16] = f2bf(v);
                        }
            }
            __syncthreads();
            unsigned short* dstp = seg == 0 ? outQ : (seg == 1 ? outK : outV);
            const int nbase = n0 & 255;
            for (int tt = tid; tt < 1024; tt += 256) {
                int row = tt >> 4, c8 = (tt & 15) * 8;
                int m = m0 + p * 64 + row, bw = m / NN, nw = m - bw * NN;
                int cc = nbase + c8;
                uint4 u = *(uint4*)&swB[row][c8];
                *(uint4*)&dstp[(((size_t)bw * NH_ + (cc >> 5)) * NN + nw) * HD_ + (cc & 31)] = u;
            }
        }
    } else {
        // ---- fp32 output: four 32-row passes through LDS, float4 RMW ----
        float (*swF)[132] = (float (*)[132])smem;     // 32x132x4 = 16896B
        #pragma unroll
        for (int p = 0; p < 4; ++p) {
            __syncthreads();
            if (wm == (p >> 1)) {
                const int mtb = (p & 1) * 2;
                #pragma unroll
                for (int mt = 0; mt < 2; ++mt)
                    #pragma unroll
                    for (int nt = 0; nt < 4; ++nt)
                        #pragma unroll
                        for (int r = 0; r < 4; ++r)
                            swF[mt * 16 + quad * 4 + r][wn * 64 + nt * 16 + l16] =
                                acc[mtb + mt][nt][r] + b4[nt];
            }
            __syncthreads();
            for (int tt = tid; tt < 1024; tt += 256) {
                int rl = tt >> 5, c4 = (tt & 31) * 4;
                size_t adr = (size_t)(m0 + p * 32 + rl) * C_ + n0 + c4;
                float4 u = *(float4*)&swF[rl][c4];
                const float4 rr = *(const float4*)&outF[adr];
                u.x += rr.x; u.y += rr.y; u.z += rr.z; u.w += rr.w;
                *(float4*)&outF[adr] = u;
            }
        }
    }
}

// ---------------- MFMA GEMM, 128x128, BK=32, depth-3 DMA (R2 config) ---------
// FC1 (GELU epilogue, ~33.5us fixed VALU): depth-3 hides a full extra step of
// staging latency; measured 62.3us in R2 vs 70.5us with depth-2 (R5).
template<int NT>
__global__ __launch_bounds__(256) void gemm3_k(
    const unsigned short* __restrict__ A, const unsigned short* __restrict__ Bt,
    int K, const float* __restrict__ bias, unsigned short* __restrict__ outB)
{
    __shared__ __align__(16) unsigned char smem[49152];
    const int tid = threadIdx.x;
    const int lin = blockIdx.x;
    const int xcd = lin & 7, t = lin >> 3;
    const int m0 = (xcd * 49 + t / NT) * 128;
    const int n0 = (t % NT) * 128;
    const int wave = tid >> 6, lane = tid & 63, quad = lane >> 4, l16 = lane & 15;
    const int wm = wave >> 1, wn = wave & 1;
    const int r0 = tid >> 2;
    const int c0 = (((tid & 3) ^ ((tid >> 3) & 3)) * 8);

    const size_t gA0 = (size_t)(m0 + r0) * K + c0;
    const size_t gA1 = (size_t)(m0 + r0 + 64) * K + c0;
    const size_t gB0 = (size_t)(n0 + r0) * K + c0;
    const size_t gB1 = (size_t)(n0 + r0 + 64) * K + c0;
    const int woff = wave * 512;
    const int sw8 = (quad ^ ((l16 >> 1) & 3)) * 8;

    f32x4 acc[4][4] = {};
    const int nk = K >> 5;
    #pragma unroll
    for (int p = 0; p < 2; ++p) {
        unsigned short* sA = (unsigned short*)(smem + p * 16384);
        unsigned short* sB = sA + 4096;
        const int kp = p << 5;
        gload_lds16(A + gA0 + kp, sA + woff);
        gload_lds16(A + gA1 + kp, sA + woff + 2048);
        gload_lds16(Bt + gB0 + kp, sB + woff);
        gload_lds16(Bt + gB1 + kp, sB + woff + 2048);
    }
    int bufc = 0;
    for (int kk = 0; kk < nk; ++kk) {
        if (kk + 2 < nk) {
            int bufn = bufc + 2; if (bufn >= 3) bufn -= 3;
            unsigned short* sA = (unsigned short*)(smem + bufn * 16384);
            unsigned short* sB = sA + 4096;
            const int k2 = (kk + 2) << 5;
            gload_lds16(A + gA0 + k2, sA + woff);
            gload_lds16(A + gA1 + k2, sA + woff + 2048);
            gload_lds16(Bt + gB0 + k2, sB + woff);
            gload_lds16(Bt + gB1 + k2, sB + woff + 2048);
            __asm volatile("s_waitcnt vmcnt(8)\n\ts_barrier" ::: "memory");
        } else if (kk + 1 < nk) {
            __asm volatile("s_waitcnt vmcnt(4)\n\ts_barrier" ::: "memory");
        } else {
            __asm volatile("s_waitcnt vmcnt(0)\n\ts_barrier" ::: "memory");
        }
        const unsigned short* sA = (const unsigned short*)(smem + bufc * 16384);
        const unsigned short* sB = sA + 4096;
        bf16x8 af[4], bfr[4];
        #pragma unroll
        for (int tt = 0; tt < 4; ++tt) {
            af[tt]  = __builtin_bit_cast(bf16x8, *(const ushort8v*)(sA + (wm * 64 + tt * 16 + l16) * 32 + sw8));
            bfr[tt] = __builtin_bit_cast(bf16x8, *(const ushort8v*)(sB + (wn * 64 + tt * 16 + l16) * 32 + sw8));
        }
        #pragma unroll
        for (int mt = 0; mt < 4; ++mt)
            #pragma unroll
            for (int nt = 0; nt < 4; ++nt)
                acc[mt][nt] = __builtin_amdgcn_mfma_f32_16x16x32_bf16(af[mt], bfr[nt], acc[mt][nt], 0, 0, 0);
        __asm volatile("s_barrier" ::: "memory");
        if (++bufc == 3) bufc = 0;
    }

    float b4[4];
    #pragma unroll
    for (int nt = 0; nt < 4; ++nt) b4[nt] = bias[n0 + wn * 64 + nt * 16 + l16];

    unsigned short (*swB)[136] = (unsigned short (*)[136])smem;  // 128x136x2 = 34816B
    #pragma unroll
    for (int mt = 0; mt < 4; ++mt)
        #pragma unroll
        for (int nt = 0; nt < 4; ++nt)
            #pragma unroll
            for (int r = 0; r < 4; ++r) {
                float v = gelu_t(acc[mt][nt][r] + b4[nt]);
                swB[wm * 64 + mt * 16 + quad * 4 + r][wn * 64 + nt * 16 + l16] = f2bf(v);
            }
    __syncthreads();
    for (int tt = tid; tt < 2048; tt += 256) {
        int row = tt >> 4, c8 = (tt & 15) * 8;
        uint4 u = *(uint4*)&swB[row][c8];
        *(uint4*)&outB[(size_t)(m0 + row) * 1024 + n0 + c8] = u;
    }
}

// ---------------- proj GEMM (64x256) + residual + fused LayerNorm2 ----------
// R9 evidence: 392-block version ran ~1.5 blk/CU (concurrency cliff from the
// R1/R2/R4 residency series). Retile BM=64: 784 blocks (~3/CU), per-wave
// acc[4][4] (proven shape); all waves share the 64-row A panel, each owns a
// 64-col slice of the 256 output cols. 5 DMA-calls/tile, depth-2, vmcnt(5).
// Epilogue unchanged: u = x + proj + bias -> out (fp32) and h2 = LN2(u).
__global__ __launch_bounds__(256) void projln_k(
    const unsigned short* __restrict__ A, const unsigned short* __restrict__ Bt,
    const float* __restrict__ bias, const float* __restrict__ resid,
    const float* __restrict__ g2, const float* __restrict__ b2,
    float* __restrict__ outF, unsigned short* __restrict__ h2)
{
    __shared__ __align__(16) unsigned char smem[40960];   // 2 x 20KB staging
    const int tid = threadIdx.x;
    const int lin = blockIdx.x;              // 784 = 8 * 98
    const int xcd = lin & 7, t = lin >> 3;
    const int m0 = (xcd * 98 + t) * 64;
    const int wave = tid >> 6, lane = tid & 63, quad = lane >> 4, l16 = lane & 15;
    const int r0 = tid >> 2;                 // 0..63
    const int c0 = (((tid & 3) ^ ((tid >> 3) & 3)) * 8);
    const int K = 256;
    const size_t gA0 = (size_t)(m0 + r0) * K + c0;
    const size_t gB0 = (size_t)(r0)       * K + c0;
    const size_t gB1 = (size_t)(r0 + 64)  * K + c0;
    const size_t gB2 = (size_t)(r0 + 128) * K + c0;
    const size_t gB3 = (size_t)(r0 + 192) * K + c0;
    const int woff = wave * 512;             // shorts
    const int sw8 = (quad ^ ((l16 >> 1) & 3)) * 8;

    f32x4 acc[4][4] = {};
    const int nk = 8;                        // K=256, BK=32

    #define PSTG(kt_, p_) { \
        unsigned short* sA_ = (unsigned short*)(smem + (p_) * 20480); \
        unsigned short* sB_ = sA_ + 2048; \
        const int kp_ = (kt_) << 5; \
        gload_lds16(A  + gA0 + kp_, sA_ + woff); \
        gload_lds16(Bt + gB0 + kp_, sB_ + woff); \
        gload_lds16(Bt + gB1 + kp_, sB_ + woff + 2048); \
        gload_lds16(Bt + gB2 + kp_, sB_ + woff + 4096); \
        gload_lds16(Bt + gB3 + kp_, sB_ + woff + 6144); }

    PSTG(0, 0);
    for (int kk = 0; kk < nk; ++kk) {
        const int p = kk & 1;
        if (kk + 1 < nk) {
            PSTG(kk + 1, p ^ 1);
            __asm volatile("s_waitcnt vmcnt(5)\n\ts_barrier" ::: "memory");
        } else {
            __asm volatile("s_waitcnt vmcnt(0)\n\ts_barrier" ::: "memory");
        }
        const unsigned short* sA = (const unsigned short*)(smem + p * 20480);
        const unsigned short* sB = sA + 2048;
        bf16x8 af[4], bfr[4];
        #pragma unroll
        for (int tt = 0; tt < 4; ++tt) {
            af[tt]  = __builtin_bit_cast(bf16x8, *(const ushort8v*)(sA + (tt * 16 + l16) * 32 + sw8));
            bfr[tt] = __builtin_bit_cast(bf16x8, *(const ushort8v*)(sB + (wave * 64 + tt * 16 + l16) * 32 + sw8));
        }
        #pragma unroll
        for (int mt = 0; mt < 4; ++mt)
            #pragma unroll
            for (int nt = 0; nt < 4; ++nt)
                acc[mt][nt] = __builtin_amdgcn_mfma_f32_16x16x32_bf16(af[mt], bfr[nt], acc[mt][nt], 0, 0, 0);
        __asm volatile("s_barrier" ::: "memory");
    }
    #undef PSTG

    float b4[4];
    #pragma unroll
    for (int nt = 0; nt < 4; ++nt) b4[nt] = bias[wave * 64 + nt * 16 + l16];
    const float4 g4  = *(const float4*)&g2[lane * 4];
    const float4 bb4 = *(const float4*)&b2[lane * 4];

    float (*swF)[260] = (float (*)[260])smem;      // 32 x 260 x 4 = 33280B
    #pragma unroll
    for (int p = 0; p < 2; ++p) {
        __syncthreads();
        {   // all waves write rows p*32..p*32+31 of their 64-col slice
            const int mtb = p * 2;
            #pragma unroll
            for (int mt = 0; mt < 2; ++mt)
                #pragma unroll
                for (int nt = 0; nt < 4; ++nt)
                    #pragma unroll
                    for (int r = 0; r < 4; ++r)
                        swF[mt * 16 + quad * 4 + r][wave * 64 + nt * 16 + l16] =
                            acc[mtb + mt][nt][r] + b4[nt];
        }
        __syncthreads();
        #pragma unroll
        for (int i = 0; i < 8; ++i) {
            int r32 = i * 4 + wave;                      // one row per wave
            int m = m0 + p * 32 + r32;
            int bw = m / NN, nw = m - bw * NN;
            int b = bw >> 6, wi = bw & 63;
            int sh = (wi >> 3) * WS_ + nw / WS_;
            int sw = (wi & 7) * WS_ + nw % WS_;
            int ph = sh + SS_; if (ph >= HH)  ph -= HH;
            int pw = sw + SS_; if (pw >= WWI) pw -= WWI;
            size_t rowadr = ((size_t)b * 3136 + ph * 56 + pw) * C_;
            float4 v = *(float4*)&swF[r32][lane * 4];
            const float4 rr = *(const float4*)&resid[rowadr + lane * 4];
            v.x += rr.x; v.y += rr.y; v.z += rr.z; v.w += rr.w;
            *(float4*)&outF[rowadr + lane * 4] = v;
            float s = v.x + v.y + v.z + v.w;
            float q = v.x*v.x + v.y*v.y + v.z*v.z + v.w*v.w;
            #pragma unroll
            for (int o = 32; o > 0; o >>= 1) { s += __shfl_xor(s, o, 64); q += __shfl_xor(q, o, 64); }
            float mu  = s * (1.0f / C_);
            float var = q * (1.0f / C_) - mu * mu;
            float rs  = rsqrtf(var + EPS_);
            float y0 = (v.x - mu) * rs * g4.x + bb4.x;
            float y1 = (v.y - mu) * rs * g4.y + bb4.y;
            float y2 = (v.z - mu) * rs * g4.z + bb4.z;
            float y3 = (v.w - mu) * rs * g4.w + bb4.w;
            unsigned int lo = (unsigned int)f2bf(y0) | ((unsigned int)f2bf(y1) << 16);
            unsigned int hi = (unsigned int)f2bf(y2) | ((unsigned int)f2bf(y3) << 16);
            uint2 uu; uu.x = lo; uu.y = hi;
            *(uint2*)&h2[rowadr + lane * 4] = uu;
        }
    }
}

// ---------------- MFMA attention: one block per (window, head) ----------------
__global__ __launch_bounds__(256) void attn_k(
    const unsigned short* __restrict__ qb, const unsigned short* __restrict__ kb,
    const unsigned short* __restrict__ vb, const unsigned short* __restrict__ cb,
    unsigned short* __restrict__ ob)
{
    __shared__ unsigned short qs[64][40];   // Q rows (pad 40: frag reads 2-way free)
    __shared__ unsigned short ks[64][40];   // K rows
    __shared__ unsigned short vt[32][72];   // V^T: [d][j], j padded to 64 (zeroed 49..63)
    __shared__ unsigned short sp[64][72];   // P bf16, A-layout rows
    __shared__ unsigned short cbs[2408];    // bias+mask slice
    const int tid = threadIdx.x;
    const int bw = blockIdx.x >> 3, head = blockIdx.x & 7;
    const size_t base = (size_t)blockIdx.x * (NN * HD_);   // (bw*8+head)*1568

    for (int t = tid; t < 588; t += 256) {
        int seg = t / 196, idx = t - seg * 196;
        int e = idx * 8;                          // 8 shorts = 16B
        const unsigned short* src = (seg == 0 ? qb : seg == 1 ? kb : vb) + base + e;
        uint4 u = *(const uint4*)src;
        if (seg == 0)      *(uint4*)&qs[e >> 5][e & 31] = u;
        else if (seg == 1) *(uint4*)&ks[e >> 5][e & 31] = u;
        else {
            int n = e >> 5, hd = e & 31;
            const unsigned short* pu = (const unsigned short*)&u;
            #pragma unroll
            for (int uu = 0; uu < 8; ++uu) vt[hd + uu][n] = pu[uu];
        }
    }
    {
        const unsigned short* cbase = cb + (size_t)(((bw & 63) * 8 + head)) * 2408;
        for (int t = tid; t < 301; t += 256)
            *(uint4*)&cbs[t * 8] = *(const uint4*)(cbase + t * 8);
        for (int t = tid; t < 480; t += 256) vt[t / 15][NN + t % 15] = 0;  // zero j=49..63
    }
    __syncthreads();

    const int wave = tid >> 6, lane = tid & 63, quad = lane >> 4, l16 = lane & 15;
    const f32x4 zz = {};

    bf16x8 afq = __builtin_bit_cast(bf16x8, *(const ushort8v*)&qs[wave * 16 + l16][quad * 8]);
    f32x4 s4[4];
    #pragma unroll
    for (int jt = 0; jt < 4; ++jt) {
        bf16x8 bk = __builtin_bit_cast(bf16x8, *(const ushort8v*)&ks[jt * 16 + l16][quad * 8]);
        s4[jt] = __builtin_amdgcn_mfma_f32_16x16x32_bf16(afq, bk, zz, 0, 0, 0);
    }

    #pragma unroll
    for (int r = 0; r < 4; ++r) {
        int i = wave * 16 + quad * 4 + r;
        float vals[4];
        #pragma unroll
        for (int jt = 0; jt < 4; ++jt) {
            int j = jt * 16 + l16;
            vals[jt] = (i < NN && j < NN) ? s4[jt][r] + bf2f(cbs[i * NN + j]) : -1e30f;
        }
        float mx = fmaxf(fmaxf(vals[0], vals[1]), fmaxf(vals[2], vals[3]));
        #pragma unroll
        for (int o = 1; o < 16; o <<= 1) mx = fmaxf(mx, __shfl_xor(mx, o, 64));
        float e[4], sum = 0.0f;
        #pragma unroll
        for (int jt = 0; jt < 4; ++jt) { e[jt] = __expf(vals[jt] - mx); sum += e[jt]; }
        #pragma unroll
        for (int o = 1; o < 16; o <<= 1) sum += __shfl_xor(sum, o, 64);
        float inv = 1.0f / sum;
        #pragma unroll
        for (int jt = 0; jt < 4; ++jt) sp[i][jt * 16 + l16] = f2bf(e[jt] * inv);
    }
    __syncthreads();

    bf16x8 ap[2];
    #pragma unroll
    for (int kt = 0; kt < 2; ++kt)
        ap[kt] = __builtin_bit_cast(bf16x8, *(const ushort8v*)&sp[wave * 16 + l16][kt * 32 + quad * 8]);
    f32x4 o4[2] = {};
    #pragma unroll
    for (int nt = 0; nt < 2; ++nt)
        #pragma unroll
        for (int kt = 0; kt < 2; ++kt) {
            bf16x8 bv = __builtin_bit_cast(bf16x8, *(const ushort8v*)&vt[nt * 16 + l16][kt * 32 + quad * 8]);
            o4[nt] = __builtin_amdgcn_mfma_f32_16x16x32_bf16(ap[kt], bv, o4[nt], 0, 0, 0);
        }
    #pragma unroll
    for (int nt = 0; nt < 2; ++nt)
        #pragma unroll
        for (int r = 0; r < 4; ++r) {
            int i = wave * 16 + quad * 4 + r;
            if (i < NN)
                ob[((size_t)bw * NN + i) * C_ + head * HD_ + nt * 16 + l16] = f2bf(o4[nt][r]);
        }
}

extern "C" void kernel_launch(void* const* d_in, const int* in_sizes, int n_in,
                              void* d_out, int out_size, void* d_ws, size_t ws_size,
                              hipStream_t stream)
{
    const float* x     = (const float*)d_in[0];
    const float* mask  = (const float*)d_in[1];
    const float* n1g   = (const float*)d_in[2];
    const float* n1b   = (const float*)d_in[3];
    const float* qkvw  = (const float*)d_in[4];
    const float* qkvb  = (const float*)d_in[5];
    const float* relb  = (const float*)d_in[6];
    const float* projw = (const float*)d_in[7];
    const float* projb = (const float*)d_in[8];
    const float* n2g   = (const float*)d_in[9];
    const float* n2b   = (const float*)d_in[10];
    const float* fc1w  = (const float*)d_in[11];
    const float* fc1b  = (const float*)d_in[12];
    const float* fc2w  = (const float*)d_in[13];
    const float* fc2b  = (const float*)d_in[14];
    float* out = (float*)d_out;

    unsigned short* wq = (unsigned short*)d_ws;   // all weights bf16, contiguous
    unsigned short* wp = wq + 196608;
    unsigned short* w1 = wq + 262144;
    unsigned short* w2 = wq + 524288;
    unsigned short* hw = wq + 786432;             // LN1-shift-partitioned (50176,256) bf16
    unsigned short* qb = hw + 12845056;           // (1024,8,49,32) bf16
    unsigned short* kb = qb + 12845056;
    unsigned short* vb = kb + 12845056;
    unsigned short* ob = vb + 12845056;           // attn out, windowed (50176,256) bf16
    unsigned short* h2 = ob + 12845056;           // LN2 out (50176,256) bf16
    unsigned short* a1 = h2 + 12845056;           // GELU(fc1) (50176,1024) bf16
    unsigned short* cbt = a1;                     // cb aliases a1 (attn_k finishes before FC1 writes a1)

    prep_k<<<3584, 256, 0, stream>>>(qkvw, projw, fc1w, fc2w, wq, mask, relb, cbt);
    ln_k<<<12544, 256, 0, stream>>>(x, n1g, n1b, hw);
    gemm_k<0, 6><<<392 * 6, 256, 0, stream>>>(hw, wq, 256, qkvb, nullptr, qb, kb, vb);
    attn_k<<<8192, 256, 0, stream>>>(qb, kb, vb, cbt, ob);
    projln_k<<<784, 256, 0, stream>>>(ob, wp, projb, x, n2g, n2b, out, h2);
    gemm3_k<8><<<392 * 8, 256, 0, stream>>>(h2, w1, 256, fc1b, a1);
    gemm_k<3, 2><<<392 * 2, 256, 0, stream>>>(a1, w2, 1024, fc2b, out, nullptr, nullptr, nullptr);
}

// Round 16
// 369.673 us; speedup vs baseline: 1.0490x; 1.0184x over previous
//
#include <hip/hip_runtime.h>
#include <cmath>

#define B_    16
#define HH    56
#define WWI   56
#define C_    256
#define NH_   8
#define WS_   7
#define SS_   3
#define HD_   32
#define NTOK  50176          // B*56*56
#define NN    49             // window size squared
#define SCALE_ 0.17677669529663689f
#define EPS_  1e-5f

typedef __bf16  bf16x8  __attribute__((ext_vector_type(8)));
typedef float   f32x4   __attribute__((ext_vector_type(4)));
typedef unsigned short ushort8v __attribute__((ext_vector_type(8)));

__device__ __forceinline__ unsigned short f2bf(float f) {
    unsigned int u = __float_as_uint(f);
    unsigned int r = u + 0x7FFFu + ((u >> 16) & 1u);   // RNE
    return (unsigned short)(r >> 16);
}
__device__ __forceinline__ float bf2f(unsigned short h) {
    return __uint_as_float(((unsigned int)h) << 16);
}
// tanh-form GELU: |err| <= ~3e-3 vs exact erf form; hw v_exp_f32 + rcp
__device__ __forceinline__ float gelu_t(float x) {
    float t = 0.7978845608028654f * (x + 0.044715f * x * x * x);
    float e = __expf(2.0f * t);
    float th = 1.0f - 2.0f * __builtin_amdgcn_rcpf(e + 1.0f);
    return 0.5f * x * (1.0f + th);
}

// async global->LDS DMA, 16B per lane; deposits at wave-uniform lds base + lane*16
__device__ __forceinline__ void gload_lds16(const unsigned short* g, unsigned short* l) {
    __builtin_amdgcn_global_load_lds(
        (const __attribute__((address_space(1))) unsigned int*)g,
        (__attribute__((address_space(3))) unsigned int*)l, 16, 0, 0);
}

// ---------------- fused prep: weights fp32->bf16 + rel-bias/mask table -------
__global__ __launch_bounds__(256) void prep_k(
    const float* __restrict__ qkvw, const float* __restrict__ projw,
    const float* __restrict__ fc1w, const float* __restrict__ fc2w,
    unsigned short* __restrict__ dst,
    const float* __restrict__ mask, const float* __restrict__ relb,
    unsigned short* __restrict__ cb)
{
    if (blockIdx.x < 3072) {
        int i = blockIdx.x * 256 + threadIdx.x;          // < 786432
        float v;
        if      (i < 196608) v = qkvw[i];
        else if (i < 262144) v = projw[i - 196608];
        else if (i < 524288) v = fc1w[i - 262144];
        else                 v = fc2w[i - 524288];
        dst[i] = f2bf(v);
    } else {
        int s = blockIdx.x - 3072;          // 512 slices = 64 windows * 8 heads
        int wi = s >> 3, head = s & 7;
        for (int p = threadIdx.x; p < 2408; p += 256) {
            float v = 0.0f;
            if (p < 2401) {
                int i = p / NN, j = p - i * NN;
                int di = i / 7 - j / 7 + 6, dj = i % 7 - j % 7 + 6;
                v = relb[(di * 13 + dj) * NH_ + head] + mask[(size_t)wi * 2401 + p];
            }
            cb[(size_t)s * 2408 + p] = f2bf(v);
        }
    }
}

// ---------------- LayerNorm1 (shift+window-partition) ------------------------
__global__ __launch_bounds__(256) void ln_k(
    const float* __restrict__ x, const float* __restrict__ g,
    const float* __restrict__ bta, unsigned short* __restrict__ dst)
{
    int wave = threadIdx.x >> 6, lane = threadIdx.x & 63;
    int tok = blockIdx.x * 4 + wave;                  // < 50176
    const float4 v = *(const float4*)(x + (size_t)tok * C_ + lane * 4);
    float s = v.x + v.y + v.z + v.w;
    float q = v.x*v.x + v.y*v.y + v.z*v.z + v.w*v.w;
    for (int o = 32; o > 0; o >>= 1) { s += __shfl_xor(s, o, 64); q += __shfl_xor(q, o, 64); }
    float mu  = s * (1.0f / C_);
    float var = q * (1.0f / C_) - mu * mu;
    float rs  = rsqrtf(var + EPS_);
    float4 gg = *(const float4*)(g   + lane * 4);
    float4 bb = *(const float4*)(bta + lane * 4);
    float y0 = (v.x - mu) * rs * gg.x + bb.x;
    float y1 = (v.y - mu) * rs * gg.y + bb.y;
    float y2 = (v.z - mu) * rs * gg.z + bb.z;
    float y3 = (v.w - mu) * rs * gg.w + bb.w;
    int b = tok / 3136, p = tok % 3136;
    int ph = p / 56, pw = p % 56;
    int sh = ph - SS_; if (sh < 0) sh += HH;
    int sw = pw - SS_; if (sw < 0) sw += WWI;
    int bw = b * 64 + (sh / WS_) * 8 + (sw / WS_);
    int n  = (sh % WS_) * WS_ + (sw % WS_);
    size_t di = ((size_t)bw * NN + n) * C_ + lane * 4;
    unsigned int lo = (unsigned int)f2bf(y0) | ((unsigned int)f2bf(y1) << 16);
    unsigned int hi = (unsigned int)f2bf(y2) | ((unsigned int)f2bf(y3) << 16);
    uint2 u; u.x = lo; u.y = hi;
    *(uint2*)(dst + di) = u;
}

// ---------------- MFMA GEMM, 128x128, BK=32, depth-2 DMA, 4 blk/CU -----------
// QKV only (EPI=0, bf16 out). T2 swizzle: slot q of row r holds global chunk
// q ^ ((r>>1)&3); linear LDS dest, pre-permuted per-lane global source; frag
// reads undo via sw8.
template<int EPI, int NT>
__global__ __launch_bounds__(256, 4) void gemm_k(
    const unsigned short* __restrict__ A, const unsigned short* __restrict__ Bt,
    int K, const float* __restrict__ bias,
    unsigned short* __restrict__ outQ, unsigned short* __restrict__ outK,
    unsigned short* __restrict__ outV)
{
    __shared__ __align__(16) unsigned char smem[32768];
    const int tid = threadIdx.x;
    const int lin = blockIdx.x;
    const int xcd = lin & 7, t = lin >> 3;
    const int m0 = (xcd * 49 + t / NT) * 128;
    const int n0 = (t % NT) * 128;
    const int wave = tid >> 6, lane = tid & 63, quad = lane >> 4, l16 = lane & 15;
    const int wm = wave >> 1, wn = wave & 1;
    const int r0 = tid >> 2;
    const int c0 = (((tid & 3) ^ ((tid >> 3) & 3)) * 8);

    const size_t gA0 = (size_t)(m0 + r0) * K + c0;
    const size_t gA1 = (size_t)(m0 + r0 + 64) * K + c0;
    const size_t gB0 = (size_t)(n0 + r0) * K + c0;
    const size_t gB1 = (size_t)(n0 + r0 + 64) * K + c0;
    const int woff = wave * 512;
    const int sw8 = (quad ^ ((l16 >> 1) & 3)) * 8;

    f32x4 acc[4][4] = {};
    const int nk = K >> 5;

    #define STAGE(kt_, p_) { \
        unsigned short* sA_ = (unsigned short*)(smem + (p_) * 16384); \
        unsigned short* sB_ = sA_ + 4096; \
        const int kp_ = (kt_) << 5; \
        gload_lds16(A + gA0 + kp_, sA_ + woff); \
        gload_lds16(A + gA1 + kp_, sA_ + woff + 2048); \
        gload_lds16(Bt + gB0 + kp_, sB_ + woff); \
        gload_lds16(Bt + gB1 + kp_, sB_ + woff + 2048); }

    STAGE(0, 0);
    for (int kk = 0; kk < nk; ++kk) {
        const int p = kk & 1;
        if (kk + 1 < nk) {
            STAGE(kk + 1, p ^ 1);
            __asm volatile("s_waitcnt vmcnt(4)\n\ts_barrier" ::: "memory");
        } else {
            __asm volatile("s_waitcnt vmcnt(0)\n\ts_barrier" ::: "memory");
        }
        const unsigned short* sA = (const unsigned short*)(smem + p * 16384);
        const unsigned short* sB = sA + 4096;
        bf16x8 af[4], bfr[4];
        #pragma unroll
        for (int tt = 0; tt < 4; ++tt) {
            af[tt]  = __builtin_bit_cast(bf16x8, *(const ushort8v*)(sA + (wm * 64 + tt * 16 + l16) * 32 + sw8));
            bfr[tt] = __builtin_bit_cast(bf16x8, *(const ushort8v*)(sB + (wn * 64 + tt * 16 + l16) * 32 + sw8));
        }
        #pragma unroll
        for (int mt = 0; mt < 4; ++mt)
            #pragma unroll
            for (int nt = 0; nt < 4; ++nt)
                acc[mt][nt] = __builtin_amdgcn_mfma_f32_16x16x32_bf16(af[mt], bfr[nt], acc[mt][nt], 0, 0, 0);
        __asm volatile("s_barrier" ::: "memory");
    }
    #undef STAGE

    float b4[4];
    #pragma unroll
    for (int nt = 0; nt < 4; ++nt) b4[nt] = bias[n0 + wn * 64 + nt * 16 + l16];

    // ---- bf16 output: two 64-row passes through LDS, packed uint4 ----
    unsigned short (*swB)[136] = (unsigned short (*)[136])smem;  // 64x136x2 = 17408B
    const int seg = n0 >> 8;                      // 0=q 1=k 2=v
    const float qs = (seg == 0) ? SCALE_ : 1.0f;
    #pragma unroll
    for (int p = 0; p < 2; ++p) {
        __syncthreads();
        if (wm == p) {
            #pragma unroll
            for (int mt = 0; mt < 4; ++mt)
                #pragma unroll
                for (int nt = 0; nt < 4; ++nt)
                    #pragma unroll
                    for (int r = 0; r < 4; ++r) {
                        float v = (acc[mt][nt][r] + b4[nt]) * qs;
                        swB[mt * 16 + quad * 4 + r][wn * 64 + nt * 16 + l16] = f2bf(v);
                    }
        }
        __syncthreads();
        unsigned short* dstp = seg == 0 ? outQ : (seg == 1 ? outK : outV);
        const int nbase = n0 & 255;
        for (int tt = tid; tt < 1024; tt += 256) {
            int row = tt >> 4, c8 = (tt & 15) * 8;
            int m = m0 + p * 64 + row, bw = m / NN, nw = m - bw * NN;
            int cc = nbase + c8;
            uint4 u = *(uint4*)&swB[row][c8];
            *(uint4*)&dstp[(((size_t)bw * NH_ + (cc >> 5)) * NN + nw) * HD_ + (cc & 31)] = u;
        }
    }
}

// ---------------- MFMA GEMM, 128x128, BK=32, depth-3 DMA (R2 config) ---------
// FC1 (GELU epilogue, ~33.5us fixed VALU): depth-3 hides a full extra step of
// staging latency; measured 62.3us in R2 vs 70.5us with depth-2 (R5).
template<int NT>
__global__ __launch_bounds__(256) void gemm3_k(
    const unsigned short* __restrict__ A, const unsigned short* __restrict__ Bt,
    int K, const float* __restrict__ bias, unsigned short* __restrict__ outB)
{
    __shared__ __align__(16) unsigned char smem[49152];
    const int tid = threadIdx.x;
    const int lin = blockIdx.x;
    const int xcd = lin & 7, t = lin >> 3;
    const int m0 = (xcd * 49 + t / NT) * 128;
    const int n0 = (t % NT) * 128;
    const int wave = tid >> 6, lane = tid & 63, quad = lane >> 4, l16 = lane & 15;
    const int wm = wave >> 1, wn = wave & 1;
    const int r0 = tid >> 2;
    const int c0 = (((tid & 3) ^ ((tid >> 3) & 3)) * 8);

    const size_t gA0 = (size_t)(m0 + r0) * K + c0;
    const size_t gA1 = (size_t)(m0 + r0 + 64) * K + c0;
    const size_t gB0 = (size_t)(n0 + r0) * K + c0;
    const size_t gB1 = (size_t)(n0 + r0 + 64) * K + c0;
    const int woff = wave * 512;
    const int sw8 = (quad ^ ((l16 >> 1) & 3)) * 8;

    f32x4 acc[4][4] = {};
    const int nk = K >> 5;
    #pragma unroll
    for (int p = 0; p < 2; ++p) {
        unsigned short* sA = (unsigned short*)(smem + p * 16384);
        unsigned short* sB = sA + 4096;
        const int kp = p << 5;
        gload_lds16(A + gA0 + kp, sA + woff);
        gload_lds16(A + gA1 + kp, sA + woff + 2048);
        gload_lds16(Bt + gB0 + kp, sB + woff);
        gload_lds16(Bt + gB1 + kp, sB + woff + 2048);
    }
    int bufc = 0;
    for (int kk = 0; kk < nk; ++kk) {
        if (kk + 2 < nk) {
            int bufn = bufc + 2; if (bufn >= 3) bufn -= 3;
            unsigned short* sA = (unsigned short*)(smem + bufn * 16384);
            unsigned short* sB = sA + 4096;
            const int k2 = (kk + 2) << 5;
            gload_lds16(A + gA0 + k2, sA + woff);
            gload_lds16(A + gA1 + k2, sA + woff + 2048);
            gload_lds16(Bt + gB0 + k2, sB + woff);
            gload_lds16(Bt + gB1 + k2, sB + woff + 2048);
            __asm volatile("s_waitcnt vmcnt(8)\n\ts_barrier" ::: "memory");
        } else if (kk + 1 < nk) {
            __asm volatile("s_waitcnt vmcnt(4)\n\ts_barrier" ::: "memory");
        } else {
            __asm volatile("s_waitcnt vmcnt(0)\n\ts_barrier" ::: "memory");
        }
        const unsigned short* sA = (const unsigned short*)(smem + bufc * 16384);
        const unsigned short* sB = sA + 4096;
        bf16x8 af[4], bfr[4];
        #pragma unroll
        for (int tt = 0; tt < 4; ++tt) {
            af[tt]  = __builtin_bit_cast(bf16x8, *(const ushort8v*)(sA + (wm * 64 + tt * 16 + l16) * 32 + sw8));
            bfr[tt] = __builtin_bit_cast(bf16x8, *(const ushort8v*)(sB + (wn * 64 + tt * 16 + l16) * 32 + sw8));
        }
        #pragma unroll
        for (int mt = 0; mt < 4; ++mt)
            #pragma unroll
            for (int nt = 0; nt < 4; ++nt)
                acc[mt][nt] = __builtin_amdgcn_mfma_f32_16x16x32_bf16(af[mt], bfr[nt], acc[mt][nt], 0, 0, 0);
        __asm volatile("s_barrier" ::: "memory");
        if (++bufc == 3) bufc = 0;
    }

    float b4[4];
    #pragma unroll
    for (int nt = 0; nt < 4; ++nt) b4[nt] = bias[n0 + wn * 64 + nt * 16 + l16];

    unsigned short (*swB)[136] = (unsigned short (*)[136])smem;  // 128x136x2 = 34816B
    #pragma unroll
    for (int mt = 0; mt < 4; ++mt)
        #pragma unroll
        for (int nt = 0; nt < 4; ++nt)
            #pragma unroll
            for (int r = 0; r < 4; ++r) {
                float v = gelu_t(acc[mt][nt][r] + b4[nt]);
                swB[wm * 64 + mt * 16 + quad * 4 + r][wn * 64 + nt * 16 + l16] = f2bf(v);
            }
    __syncthreads();
    for (int tt = tid; tt < 2048; tt += 256) {
        int row = tt >> 4, c8 = (tt & 15) * 8;
        uint4 u = *(uint4*)&swB[row][c8];
        *(uint4*)&outB[(size_t)(m0 + row) * 1024 + n0 + c8] = u;
    }
}

// ---------------- MFMA GEMM, 128x128, BK=32, depth-3 DMA, fp32 RMW out -------
// FC2 (K=1024, nk=32): R2 measured 62.9us with this exact structure; depth-2
// variants measured 70-81us (R5/R9/R14). Long-K wants two tiles in flight
// across the barrier more than a 4th resident block. Epilogue: two 64-row
// passes through LDS, float4 RMW into outF (residual already there).
template<int NT>
__global__ __launch_bounds__(256) void gemm3f_k(
    const unsigned short* __restrict__ A, const unsigned short* __restrict__ Bt,
    int K, const float* __restrict__ bias, float* __restrict__ outF)
{
    __shared__ __align__(16) unsigned char smem[49152];
    const int tid = threadIdx.x;
    const int lin = blockIdx.x;
    const int xcd = lin & 7, t = lin >> 3;
    const int m0 = (xcd * 49 + t / NT) * 128;
    const int n0 = (t % NT) * 128;
    const int wave = tid >> 6, lane = tid & 63, quad = lane >> 4, l16 = lane & 15;
    const int wm = wave >> 1, wn = wave & 1;
    const int r0 = tid >> 2;
    const int c0 = (((tid & 3) ^ ((tid >> 3) & 3)) * 8);

    const size_t gA0 = (size_t)(m0 + r0) * K + c0;
    const size_t gA1 = (size_t)(m0 + r0 + 64) * K + c0;
    const size_t gB0 = (size_t)(n0 + r0) * K + c0;
    const size_t gB1 = (size_t)(n0 + r0 + 64) * K + c0;
    const int woff = wave * 512;
    const int sw8 = (quad ^ ((l16 >> 1) & 3)) * 8;

    f32x4 acc[4][4] = {};
    const int nk = K >> 5;
    #pragma unroll
    for (int p = 0; p < 2; ++p) {
        unsigned short* sA = (unsigned short*)(smem + p * 16384);
        unsigned short* sB = sA + 4096;
        const int kp = p << 5;
        gload_lds16(A + gA0 + kp, sA + woff);
        gload_lds16(A + gA1 + kp, sA + woff + 2048);
        gload_lds16(Bt + gB0 + kp, sB + woff);
        gload_lds16(Bt + gB1 + kp, sB + woff + 2048);
    }
    int bufc = 0;
    for (int kk = 0; kk < nk; ++kk) {
        if (kk + 2 < nk) {
            int bufn = bufc + 2; if (bufn >= 3) bufn -= 3;
            unsigned short* sA = (unsigned short*)(smem + bufn * 16384);
            unsigned short* sB = sA + 4096;
            const int k2 = (kk + 2) << 5;
            gload_lds16(A + gA0 + k2, sA + woff);
            gload_lds16(A + gA1 + k2, sA + woff + 2048);
            gload_lds16(Bt + gB0 + k2, sB + woff);
            gload_lds16(Bt + gB1 + k2, sB + woff + 2048);
            __asm volatile("s_waitcnt vmcnt(8)\n\ts_barrier" ::: "memory");
        } else if (kk + 1 < nk) {
            __asm volatile("s_waitcnt vmcnt(4)\n\ts_barrier" ::: "memory");
        } else {
            __asm volatile("s_waitcnt vmcnt(0)\n\ts_barrier" ::: "memory");
        }
        const unsigned short* sA = (const unsigned short*)(smem + bufc * 16384);
        const unsigned short* sB = sA + 4096;
        bf16x8 af[4], bfr[4];
        #pragma unroll
        for (int tt = 0; tt < 4; ++tt) {
            af[tt]  = __builtin_bit_cast(bf16x8, *(const ushort8v*)(sA + (wm * 64 + tt * 16 + l16) * 32 + sw8));
            bfr[tt] = __builtin_bit_cast(bf16x8, *(const ushort8v*)(sB + (wn * 64 + tt * 16 + l16) * 32 + sw8));
        }
        #pragma unroll
        for (int mt = 0; mt < 4; ++mt)
            #pragma unroll
            for (int nt = 0; nt < 4; ++nt)
                acc[mt][nt] = __builtin_amdgcn_mfma_f32_16x16x32_bf16(af[mt], bfr[nt], acc[mt][nt], 0, 0, 0);
        __asm volatile("s_barrier" ::: "memory");
        if (++bufc == 3) bufc = 0;
    }

    float b4[4];
    #pragma unroll
    for (int nt = 0; nt < 4; ++nt) b4[nt] = bias[n0 + wn * 64 + nt * 16 + l16];

    // fp32 output: two 64-row passes through LDS, float4 RMW
    float (*swF)[132] = (float (*)[132])smem;     // 64x132x4 = 33792B
    #pragma unroll
    for (int p = 0; p < 2; ++p) {
        __syncthreads();
        if (wm == p) {
            #pragma unroll
            for (int mt = 0; mt < 4; ++mt)
                #pragma unroll
                for (int nt = 0; nt < 4; ++nt)
                    #pragma unroll
                    for (int r = 0; r < 4; ++r)
                        swF[mt * 16 + quad * 4 + r][wn * 64 + nt * 16 + l16] = acc[mt][nt][r] + b4[nt];
        }
        __syncthreads();
        for (int tt = tid; tt < 2048; tt += 256) {
            int rl = tt >> 5, c4 = (tt & 31) * 4;
            size_t adr = (size_t)(m0 + p * 64 + rl) * C_ + n0 + c4;
            float4 u = *(float4*)&swF[rl][c4];
            const float4 rr = *(const float4*)&outF[adr];
            u.x += rr.x; u.y += rr.y; u.z += rr.z; u.w += rr.w;
            *(float4*)&outF[adr] = u;
        }
    }
}

// ---------------- proj GEMM (64x256) + residual + fused LayerNorm2 ----------
// 784 blocks (~3/CU, off the R9 concurrency cliff); per-wave acc[4][4];
// all waves share the 64-row A panel, each owns a 64-col slice.
// Epilogue: u = x + proj + bias -> out (fp32) and h2 = LN2(u).
__global__ __launch_bounds__(256) void projln_k(
    const unsigned short* __restrict__ A, const unsigned short* __restrict__ Bt,
    const float* __restrict__ bias, const float* __restrict__ resid,
    const float* __restrict__ g2, const float* __restrict__ b2,
    float* __restrict__ outF, unsigned short* __restrict__ h2)
{
    __shared__ __align__(16) unsigned char smem[40960];   // 2 x 20KB staging
    const int tid = threadIdx.x;
    const int lin = blockIdx.x;              // 784 = 8 * 98
    const int xcd = lin & 7, t = lin >> 3;
    const int m0 = (xcd * 98 + t) * 64;
    const int wave = tid >> 6, lane = tid & 63, quad = lane >> 4, l16 = lane & 15;
    const int r0 = tid >> 2;                 // 0..63
    const int c0 = (((tid & 3) ^ ((tid >> 3) & 3)) * 8);
    const int K = 256;
    const size_t gA0 = (size_t)(m0 + r0) * K + c0;
    const size_t gB0 = (size_t)(r0)       * K + c0;
    const size_t gB1 = (size_t)(r0 + 64)  * K + c0;
    const size_t gB2 = (size_t)(r0 + 128) * K + c0;
    const size_t gB3 = (size_t)(r0 + 192) * K + c0;
    const int woff = wave * 512;             // shorts
    const int sw8 = (quad ^ ((l16 >> 1) & 3)) * 8;

    f32x4 acc[4][4] = {};
    const int nk = 8;                        // K=256, BK=32

    #define PSTG(kt_, p_) { \
        unsigned short* sA_ = (unsigned short*)(smem + (p_) * 20480); \
        unsigned short* sB_ = sA_ + 2048; \
        const int kp_ = (kt_) << 5; \
        gload_lds16(A  + gA0 + kp_, sA_ + woff); \
        gload_lds16(Bt + gB0 + kp_, sB_ + woff); \
        gload_lds16(Bt + gB1 + kp_, sB_ + woff + 2048); \
        gload_lds16(Bt + gB2 + kp_, sB_ + woff + 4096); \
        gload_lds16(Bt + gB3 + kp_, sB_ + woff + 6144); }

    PSTG(0, 0);
    for (int kk = 0; kk < nk; ++kk) {
        const int p = kk & 1;
        if (kk + 1 < nk) {
            PSTG(kk + 1, p ^ 1);
            __asm volatile("s_waitcnt vmcnt(5)\n\ts_barrier" ::: "memory");
        } else {
            __asm volatile("s_waitcnt vmcnt(0)\n\ts_barrier" ::: "memory");
        }
        const unsigned short* sA = (const unsigned short*)(smem + p * 20480);
        const unsigned short* sB = sA + 2048;
        bf16x8 af[4], bfr[4];
        #pragma unroll
        for (int tt = 0; tt < 4; ++tt) {
            af[tt]  = __builtin_bit_cast(bf16x8, *(const ushort8v*)(sA + (tt * 16 + l16) * 32 + sw8));
            bfr[tt] = __builtin_bit_cast(bf16x8, *(const ushort8v*)(sB + (wave * 64 + tt * 16 + l16) * 32 + sw8));
        }
        #pragma unroll
        for (int mt = 0; mt < 4; ++mt)
            #pragma unroll
            for (int nt = 0; nt < 4; ++nt)
                acc[mt][nt] = __builtin_amdgcn_mfma_f32_16x16x32_bf16(af[mt], bfr[nt], acc[mt][nt], 0, 0, 0);
        __asm volatile("s_barrier" ::: "memory");
    }
    #undef PSTG

    float b4[4];
    #pragma unroll
    for (int nt = 0; nt < 4; ++nt) b4[nt] = bias[wave * 64 + nt * 16 + l16];
    const float4 g4  = *(const float4*)&g2[lane * 4];
    const float4 bb4 = *(const float4*)&b2[lane * 4];

    float (*swF)[260] = (float (*)[260])smem;      // 32 x 260 x 4 = 33280B
    #pragma unroll
    for (int p = 0; p < 2; ++p) {
        __syncthreads();
        {   // all waves write rows p*32..p*32+31 of their 64-col slice
            const int mtb = p * 2;
            #pragma unroll
            for (int mt = 0; mt < 2; ++mt)
                #pragma unroll
                for (int nt = 0; nt < 4; ++nt)
                    #pragma unroll
                    for (int r = 0; r < 4; ++r)
                        swF[mt * 16 + quad * 4 + r][wave * 64 + nt * 16 + l16] =
                            acc[mtb + mt][nt][r] + b4[nt];
        }
        __syncthreads();
        #pragma unroll
        for (int i = 0; i < 8; ++i) {
            int r32 = i * 4 + wave;                      // one row per wave
            int m = m0 + p * 32 + r32;
            int bw = m / NN, nw = m - bw * NN;
            int b = bw >> 6, wi = bw & 63;
            int sh = (wi >> 3) * WS_ + nw / WS_;
            int sw = (wi & 7) * WS_ + nw % WS_;
            int ph = sh + SS_; if (ph >= HH)  ph -= HH;
            int pw = sw + SS_; if (pw >= WWI) pw -= WWI;
            size_t rowadr = ((size_t)b * 3136 + ph * 56 + pw) * C_;
            float4 v = *(float4*)&swF[r32][lane * 4];
            const float4 rr = *(const float4*)&resid[rowadr + lane * 4];
            v.x += rr.x; v.y += rr.y; v.z += rr.z; v.w += rr.w;
            *(float4*)&outF[rowadr + lane * 4] = v;
            float s = v.x + v.y + v.z + v.w;
            float q = v.x*v.x + v.y*v.y + v.z*v.z + v.w*v.w;
            #pragma unroll
            for (int o = 32; o > 0; o >>= 1) { s += __shfl_xor(s, o, 64); q += __shfl_xor(q, o, 64); }
            float mu  = s * (1.0f / C_);
            float var = q * (1.0f / C_) - mu * mu;
            float rs  = rsqrtf(var + EPS_);
            float y0 = (v.x - mu) * rs * g4.x + bb4.x;
            float y1 = (v.y - mu) * rs * g4.y + bb4.y;
            float y2 = (v.z - mu) * rs * g4.z + bb4.z;
            float y3 = (v.w - mu) * rs * g4.w + bb4.w;
            unsigned int lo = (unsigned int)f2bf(y0) | ((unsigned int)f2bf(y1) << 16);
            unsigned int hi = (unsigned int)f2bf(y2) | ((unsigned int)f2bf(y3) << 16);
            uint2 uu; uu.x = lo; uu.y = hi;
            *(uint2*)&h2[rowadr + lane * 4] = uu;
        }
    }
}

// ---------------- MFMA attention: one block per (window, head) ----------------
__global__ __launch_bounds__(256) void attn_k(
    const unsigned short* __restrict__ qb, const unsigned short* __restrict__ kb,
    const unsigned short* __restrict__ vb, const unsigned short* __restrict__ cb,
    unsigned short* __restrict__ ob)
{
    __shared__ unsigned short qs[64][40];   // Q rows (pad 40: frag reads 2-way free)
    __shared__ unsigned short ks[64][40];   // K rows
    __shared__ unsigned short vt[32][72];   // V^T: [d][j], j padded to 64 (zeroed 49..63)
    __shared__ unsigned short sp[64][72];   // P bf16, A-layout rows
    __shared__ unsigned short cbs[2408];    // bias+mask slice
    const int tid = threadIdx.x;
    const int bw = blockIdx.x >> 3, head = blockIdx.x & 7;
    const size_t base = (size_t)blockIdx.x * (NN * HD_);   // (bw*8+head)*1568

    for (int t = tid; t < 588; t += 256) {
        int seg = t / 196, idx = t - seg * 196;
        int e = idx * 8;                          // 8 shorts = 16B
        const unsigned short* src = (seg == 0 ? qb : seg == 1 ? kb : vb) + base + e;
        uint4 u = *(const uint4*)src;
        if (seg == 0)      *(uint4*)&qs[e >> 5][e & 31] = u;
        else if (seg == 1) *(uint4*)&ks[e >> 5][e & 31] = u;
        else {
            int n = e >> 5, hd = e & 31;
            const unsigned short* pu = (const unsigned short*)&u;
            #pragma unroll
            for (int uu = 0; uu < 8; ++uu) vt[hd + uu][n] = pu[uu];
        }
    }
    {
        const unsigned short* cbase = cb + (size_t)(((bw & 63) * 8 + head)) * 2408;
        for (int t = tid; t < 301; t += 256)
            *(uint4*)&cbs[t * 8] = *(const uint4*)(cbase + t * 8);
        for (int t = tid; t < 480; t += 256) vt[t / 15][NN + t % 15] = 0;  // zero j=49..63
    }
    __syncthreads();

    const int wave = tid >> 6, lane = tid & 63, quad = lane >> 4, l16 = lane & 15;
    const f32x4 zz = {};

    bf16x8 afq = __builtin_bit_cast(bf16x8, *(const ushort8v*)&qs[wave * 16 + l16][quad * 8]);
    f32x4 s4[4];
    #pragma unroll
    for (int jt = 0; jt < 4; ++jt) {
        bf16x8 bk = __builtin_bit_cast(bf16x8, *(const ushort8v*)&ks[jt * 16 + l16][quad * 8]);
        s4[jt] = __builtin_amdgcn_mfma_f32_16x16x32_bf16(afq, bk, zz, 0, 0, 0);
    }

    #pragma unroll
    for (int r = 0; r < 4; ++r) {
        int i = wave * 16 + quad * 4 + r;
        float vals[4];
        #pragma unroll
        for (int jt = 0; jt < 4; ++jt) {
            int j = jt * 16 + l16;
            vals[jt] = (i < NN && j < NN) ? s4[jt][r] + bf2f(cbs[i * NN + j]) : -1e30f;
        }
        float mx = fmaxf(fmaxf(vals[0], vals[1]), fmaxf(vals[2], vals[3]));
        #pragma unroll
        for (int o = 1; o < 16; o <<= 1) mx = fmaxf(mx, __shfl_xor(mx, o, 64));
        float e[4], sum = 0.0f;
        #pragma unroll
        for (int jt = 0; jt < 4; ++jt) { e[jt] = __expf(vals[jt] - mx); sum += e[jt]; }
        #pragma unroll
        for (int o = 1; o < 16; o <<= 1) sum += __shfl_xor(sum, o, 64);
        float inv = 1.0f / sum;
        #pragma unroll
        for (int jt = 0; jt < 4; ++jt) sp[i][jt * 16 + l16] = f2bf(e[jt] * inv);
    }
    __syncthreads();

    bf16x8 ap[2];
    #pragma unroll
    for (int kt = 0; kt < 2; ++kt)
        ap[kt] = __builtin_bit_cast(bf16x8, *(const ushort8v*)&sp[wave * 16 + l16][kt * 32 + quad * 8]);
    f32x4 o4[2] = {};
    #pragma unroll
    for (int nt = 0; nt < 2; ++nt)
        #pragma unroll
        for (int kt = 0; kt < 2; ++kt) {
            bf16x8 bv = __builtin_bit_cast(bf16x8, *(const ushort8v*)&vt[nt * 16 + l16][kt * 32 + quad * 8]);
            o4[nt] = __builtin_amdgcn_mfma_f32_16x16x32_bf16(ap[kt], bv, o4[nt], 0, 0, 0);
        }
    #pragma unroll
    for (int nt = 0; nt < 2; ++nt)
        #pragma unroll
        for (int r = 0; r < 4; ++r) {
            int i = wave * 16 + quad * 4 + r;
            if (i < NN)
                ob[((size_t)bw * NN + i) * C_ + head * HD_ + nt * 16 + l16] = f2bf(o4[nt][r]);
        }
}

extern "C" void kernel_launch(void* const* d_in, const int* in_sizes, int n_in,
                              void* d_out, int out_size, void* d_ws, size_t ws_size,
                              hipStream_t stream)
{
    const float* x     = (const float*)d_in[0];
    const float* mask  = (const float*)d_in[1];
    const float* n1g   = (const float*)d_in[2];
    const float* n1b   = (const float*)d_in[3];
    const float* qkvw  = (const float*)d_in[4];
    const float* qkvb  = (const float*)d_in[5];
    const float* relb  = (const float*)d_in[6];
    const float* projw = (const float*)d_in[7];
    const float* projb = (const float*)d_in[8];
    const float* n2g   = (const float*)d_in[9];
    const float* n2b   = (const float*)d_in[10];
    const float* fc1w  = (const float*)d_in[11];
    const float* fc1b  = (const float*)d_in[12];
    const float* fc2w  = (const float*)d_in[13];
    const float* fc2b  = (const float*)d_in[14];
    float* out = (float*)d_out;

    unsigned short* wq = (unsigned short*)d_ws;   // all weights bf16, contiguous
    unsigned short* wp = wq + 196608;
    unsigned short* w1 = wq + 262144;
    unsigned short* w2 = wq + 524288;
    unsigned short* hw = wq + 786432;             // LN1-shift-partitioned (50176,256) bf16
    unsigned short* qb = hw + 12845056;           // (1024,8,49,32) bf16
    unsigned short* kb = qb + 12845056;
    unsigned short* vb = kb + 12845056;
    unsigned short* ob = vb + 12845056;           // attn out, windowed (50176,256) bf16
    unsigned short* h2 = ob + 12845056;           // LN2 out (50176,256) bf16
    unsigned short* a1 = h2 + 12845056;           // GELU(fc1) (50176,1024) bf16
    unsigned short* cbt = a1;                     // cb aliases a1 (attn_k finishes before FC1 writes a1)

    prep_k<<<3584, 256, 0, stream>>>(qkvw, projw, fc1w, fc2w, wq, mask, relb, cbt);
    ln_k<<<12544, 256, 0, stream>>>(x, n1g, n1b, hw);
    gemm_k<0, 6><<<392 * 6, 256, 0, stream>>>(hw, wq, 256, qkvb, qb, kb, vb);
    attn_k<<<8192, 256, 0, stream>>>(qb, kb, vb, cbt, ob);
    projln_k<<<784, 256, 0, stream>>>(ob, wp, projb, x, n2g, n2b, out, h2);
    gemm3_k<8><<<392 * 8, 256, 0, stream>>>(h2, w1, 256, fc1b, a1);
    gemm3f_k<2><<<392 * 2, 256, 0, stream>>>(a1, w2, 1024, fc2b, out);
}